// Round 4
// baseline (562.665 us; speedup 1.0000x reference)
//
#include <hip/hip_runtime.h>

typedef __attribute__((ext_vector_type(8))) short bf16x8;
typedef __attribute__((ext_vector_type(4))) float f32x4;
typedef unsigned short u16;
typedef unsigned int   u32;

__device__ __forceinline__ u16 f2bf(float f) {
  u32 u = __builtin_bit_cast(u32, f);
  u = (u + 0x7FFFu + ((u >> 16) & 1u)) >> 16;
  return (u16)u;
}

// ws layout (bytes):
//      0 : Wq|Wk|Wv bf16 [3][256][256]           (393216 B)
// 393216 : rpbT f32 [8][64][64]  rpbT[h][q][k] = bias_table[rel_index[q][k]][h]
// total 524288 B

__global__ void prep_kernel(const float* __restrict__ Wq, const float* __restrict__ Wk,
                            const float* __restrict__ Wv, const float* __restrict__ btab,
                            const int* __restrict__ ridx, u16* __restrict__ wb,
                            float* __restrict__ rpbT) {
  int bid = blockIdx.x, tid = threadIdx.x;
  if (bid < 768) {
    int gid = bid * 256 + tid;                  // 3 x 65536 weights
    int m = gid >> 16, e = gid & 65535;
    const float* W = (m == 0) ? Wq : (m == 1) ? Wk : Wv;
    wb[gid] = f2bf(W[e]);
  } else {
    int e = (bid - 768) * 256 + tid;            // 32768 elems, [h][q][k], k fastest
    int k = e & 63, q = (e >> 6) & 63, h = e >> 12;
    rpbT[e] = btab[ridx[q * 64 + k] * 8 + h];
  }
}

// One block per window; 4 waves; wave w owns heads 2w, 2w+1 (one at a time).
// LDS 80 KiB:
//   [0,32K)        Xs [64][256] bf16, XOR-swizzled rows of 512B
//   32K + w*12K:   per-wave scratch, 12 KiB:
//     +0    Kh [64][32] bf16, 64B rows, 16B-block rotation by (row>>1)&3
//     +4096 Qh  same layout, pre-scaled by 1/sqrt(32)
//     +8192 VT [32][64] bf16, 128B rows, XOR ^((d&7)<<4)
//     P  [64][64] bf16 overlays Kh+Qh (8K)  (barrier-separated)
//     O  [64][32] f32  overlays P           (barrier-separated)
// All LDS phase transitions are separated by __syncthreads() (uniform flow).
__global__ __launch_bounds__(256, 2) void swin_attn_kernel(
    const float* __restrict__ X, const u16* __restrict__ Wb,
    const float* __restrict__ bq, const float* __restrict__ bk,
    const float* __restrict__ bv, const float* __restrict__ rpbT,
    const float* __restrict__ amask, float* __restrict__ out) {
  __shared__ char smem[81920];

  const int tid = threadIdx.x;
  const int l  = tid & 63;
  const int w  = tid >> 6;
  const int lr = l & 15;
  const int lg = l >> 4;
  const int b  = blockIdx.x;
  const int win = b & 63;

  const float* Xb = X + (size_t)b * (64 * 256);
  float* ob = out + (size_t)b * (64 * 256);

  // ---- stage X -> bf16 LDS ----
#pragma unroll
  for (int it = 0; it < 8; ++it) {
    int c = tid + it * 256;
    int r = c >> 5;
    int k0 = (c & 31) << 3;
    const float* xp = Xb + r * 256 + k0;
    float4 f0 = *(const float4*)xp;
    float4 f1 = *(const float4*)(xp + 4);
    int p0 = (int)((u32)f2bf(f0.x) | ((u32)f2bf(f0.y) << 16));
    int p1 = (int)((u32)f2bf(f0.z) | ((u32)f2bf(f0.w) << 16));
    int p2 = (int)((u32)f2bf(f1.x) | ((u32)f2bf(f1.y) << 16));
    int p3 = (int)((u32)f2bf(f1.z) | ((u32)f2bf(f1.w) << 16));
    int off = (r * 512 + k0 * 2) ^ ((r & 7) << 4);
    *(int4*)(smem + off) = make_int4(p0, p1, p2, p3);
  }
  __syncthreads();

  char* const Kb = smem + 32768 + w * 12288;
  char* const Qb = Kb + 4096;
  char* const Vb = Kb + 8192;
  char* const Pb = Kb;        // overlays K+Q
  char* const Ob = Kb;        // overlays P

  const float SCALE = 0.17677669529663687f;  // 1/sqrt(32)
  const f32x4 zero = (f32x4)(0.f);

  for (int hl = 0; hl < 2; ++hl) {
    const int h = w * 2 + hl;
    const int cb = w * 64 + hl * 32;     // global channel base of this head

    // ================= V projection (64x32), write VT =================
    {
      float bsv[2];
#pragma unroll
      for (int jf = 0; jf < 2; ++jf) bsv[jf] = bv[cb + jf * 16 + lr];
      f32x4 av[4][2];
#pragma unroll
      for (int rf = 0; rf < 4; ++rf) { av[rf][0] = zero; av[rf][1] = zero; }
#pragma unroll
      for (int ks = 0; ks < 8; ++ks) {
        int kb = ks * 32 + lg * 8;
        bf16x8 a[4];
#pragma unroll
        for (int rf = 0; rf < 4; ++rf) {
          int row = lr + rf * 16;
          a[rf] = *(const bf16x8*)(smem + ((row * 512 + kb * 2) ^ ((row & 7) << 4)));
        }
#pragma unroll
        for (int jf = 0; jf < 2; ++jf) {
          bf16x8 wv = *(const bf16x8*)(Wb + 131072 + (cb + jf * 16 + lr) * 256 + kb);
#pragma unroll
          for (int rf = 0; rf < 4; ++rf)
            av[rf][jf] = __builtin_amdgcn_mfma_f32_16x16x32_bf16(a[rf], wv, av[rf][jf], 0, 0, 0);
        }
      }
#pragma unroll
      for (int rf = 0; rf < 4; ++rf)
#pragma unroll
        for (int jf = 0; jf < 2; ++jf) {
          int dloc = jf * 16 + lr;
          int i0 = lg * 4 + rf * 16;
          u32 lo = (u32)f2bf(av[rf][jf][0] + bsv[jf]) | ((u32)f2bf(av[rf][jf][1] + bsv[jf]) << 16);
          u32 hi = (u32)f2bf(av[rf][jf][2] + bsv[jf]) | ((u32)f2bf(av[rf][jf][3] + bsv[jf]) << 16);
          int voff = (dloc * 128 + i0 * 2) ^ ((dloc & 7) << 4);
          *(uint2*)(Vb + voff) = make_uint2(lo, hi);
        }
    }

    // ================= Q,K projection (64x32 each), write rotated =================
    {
      float bsq[2], bsk[2];
#pragma unroll
      for (int jf = 0; jf < 2; ++jf) {
        bsq[jf] = bq[cb + jf * 16 + lr];
        bsk[jf] = bk[cb + jf * 16 + lr];
      }
      f32x4 aq[4][2], ak[4][2];
#pragma unroll
      for (int rf = 0; rf < 4; ++rf)
#pragma unroll
        for (int jf = 0; jf < 2; ++jf) { aq[rf][jf] = zero; ak[rf][jf] = zero; }
#pragma unroll
      for (int ks = 0; ks < 8; ++ks) {
        int kb = ks * 32 + lg * 8;
        bf16x8 a[4];
#pragma unroll
        for (int rf = 0; rf < 4; ++rf) {
          int row = lr + rf * 16;
          a[rf] = *(const bf16x8*)(smem + ((row * 512 + kb * 2) ^ ((row & 7) << 4)));
        }
#pragma unroll
        for (int jf = 0; jf < 2; ++jf) {
          int wr = (cb + jf * 16 + lr) * 256 + kb;
          bf16x8 wq = *(const bf16x8*)(Wb + wr);
          bf16x8 wk = *(const bf16x8*)(Wb + 65536 + wr);
#pragma unroll
          for (int rf = 0; rf < 4; ++rf) {
            aq[rf][jf] = __builtin_amdgcn_mfma_f32_16x16x32_bf16(a[rf], wq, aq[rf][jf], 0, 0, 0);
            ak[rf][jf] = __builtin_amdgcn_mfma_f32_16x16x32_bf16(a[rf], wk, ak[rf][jf], 0, 0, 0);
          }
        }
      }
#pragma unroll
      for (int rf = 0; rf < 4; ++rf)
#pragma unroll
        for (int jf = 0; jf < 2; ++jf) {
          int dloc = jf * 16 + lr;
#pragma unroll
          for (int reg = 0; reg < 4; ++reg) {
            int i = lg * 4 + reg + rf * 16;
            int off = i * 64 + ((dloc * 2 + (((i >> 1) & 3) << 4)) & 63);
            *(u16*)(Qb + off) = f2bf((aq[rf][jf][reg] + bsq[jf]) * SCALE);
            *(u16*)(Kb + off) = f2bf(ak[rf][jf][reg] + bsk[jf]);
          }
        }
    }
    __syncthreads();   // K/Q/V written -> S-phase reads

    // ================= S^T = K @ Q^T (rows k-token, cols q), + bias + mask =================
    float p[4][4][4];  // [rf(k-blocks)][cf(q-blocks)][reg]
    {
      bf16x8 fK[4], fQ[4];
#pragma unroll
      for (int rf = 0; rf < 4; ++rf) {
        int row = lr + rf * 16;
        int off = row * 64 + (((lg + ((row >> 1) & 3)) & 3) << 4);
        fK[rf] = *(const bf16x8*)(Kb + off);
        fQ[rf] = *(const bf16x8*)(Qb + off);
      }
      const float* rp = rpbT + h * 4096;        // [q][k]
      const float* mp = amask + win * 4096;     // [q][k]
#pragma unroll
      for (int rf = 0; rf < 4; ++rf)
#pragma unroll
        for (int cf = 0; cf < 4; ++cf) {
          f32x4 st = __builtin_amdgcn_mfma_f32_16x16x32_bf16(fK[rf], fQ[cf], zero, 0, 0, 0);
          int q = lr + cf * 16;
          int klo = lg * 4 + rf * 16;
          float4 rv = *(const float4*)(rp + q * 64 + klo);
          float4 mv = *(const float4*)(mp + q * 64 + klo);
          p[rf][cf][0] = st[0] + rv.x + mv.x;
          p[rf][cf][1] = st[1] + rv.y + mv.y;
          p[rf][cf][2] = st[2] + rv.z + mv.z;
          p[rf][cf][3] = st[3] + rv.w + mv.w;
        }
    }

    // ================= softmax over k per column q =================
#pragma unroll
    for (int cf = 0; cf < 4; ++cf) {
      float mx = p[0][cf][0];
#pragma unroll
      for (int rf = 0; rf < 4; ++rf)
#pragma unroll
        for (int reg = 0; reg < 4; ++reg) mx = fmaxf(mx, p[rf][cf][reg]);
      mx = fmaxf(mx, __shfl_xor(mx, 16));
      mx = fmaxf(mx, __shfl_xor(mx, 32));
      float sum = 0.f;
#pragma unroll
      for (int rf = 0; rf < 4; ++rf)
#pragma unroll
        for (int reg = 0; reg < 4; ++reg) {
          float e = exp2f((p[rf][cf][reg] - mx) * 1.4426950408889634f);
          p[rf][cf][reg] = e;
          sum += e;
        }
      sum += __shfl_xor(sum, 16);
      sum += __shfl_xor(sum, 32);
      float rs = 1.0f / sum;
#pragma unroll
      for (int rf = 0; rf < 4; ++rf)
#pragma unroll
        for (int reg = 0; reg < 4; ++reg) p[rf][cf][reg] *= rs;
    }
    __syncthreads();   // S-phase LDS reads done -> P may overlay K/Q

    // ================= P -> LDS [q][k] bf16 =================
#pragma unroll
    for (int rf = 0; rf < 4; ++rf)
#pragma unroll
      for (int cf = 0; cf < 4; ++cf) {
        int q = lr + cf * 16;
        int k0 = lg * 4 + rf * 16;
        u32 lo = (u32)f2bf(p[rf][cf][0]) | ((u32)f2bf(p[rf][cf][1]) << 16);
        u32 hi = (u32)f2bf(p[rf][cf][2]) | ((u32)f2bf(p[rf][cf][3]) << 16);
        int off = (q * 128 + k0 * 2) ^ ((q & 7) << 4);
        *(uint2*)(Pb + off) = make_uint2(lo, hi);
      }
    __syncthreads();   // P written -> PV reads

    // ================= PV: ctx[64 q][32 d] =================
    f32x4 o[4][2];
#pragma unroll
    for (int rf = 0; rf < 4; ++rf) { o[rf][0] = zero; o[rf][1] = zero; }
#pragma unroll
    for (int ks2 = 0; ks2 < 2; ++ks2) {
      int kb2 = (ks2 * 32 + lg * 8) * 2;
      bf16x8 aP[4];
#pragma unroll
      for (int rf = 0; rf < 4; ++rf) {
        int row = lr + rf * 16;
        aP[rf] = *(const bf16x8*)(Pb + ((row * 128 + kb2) ^ ((row & 7) << 4)));
      }
#pragma unroll
      for (int jf = 0; jf < 2; ++jf) {
        int vr = jf * 16 + lr;
        bf16x8 bV = *(const bf16x8*)(Vb + ((vr * 128 + kb2) ^ ((vr & 7) << 4)));
#pragma unroll
        for (int rf = 0; rf < 4; ++rf)
          o[rf][jf] = __builtin_amdgcn_mfma_f32_16x16x32_bf16(aP[rf], bV, o[rf][jf], 0, 0, 0);
      }
    }
    __syncthreads();   // PV LDS reads done -> O may overlay P

    // ================= ctx -> LDS f32, then coalesced float4 stores =================
#pragma unroll
    for (int rf = 0; rf < 4; ++rf)
#pragma unroll
      for (int jf = 0; jf < 2; ++jf)
#pragma unroll
        for (int reg = 0; reg < 4; ++reg) {
          int i = lg * 4 + reg + rf * 16;
          int dloc = jf * 16 + lr;
          int off = (i * 128 + dloc * 4) ^ ((i & 4) << 4);
          *(float*)(Ob + off) = o[rf][jf][reg];
        }
    __syncthreads();   // O written -> O reads
#pragma unroll
    for (int e = 0; e < 8; ++e) {
      int idx = l + e * 64;
      int row = idx >> 3;
      int c = idx & 7;
      float4 v = *(const float4*)(Ob + ((row * 128 + c * 16) ^ ((row & 4) << 4)));
      *(float4*)(ob + row * 256 + cb + c * 4) = v;
    }
    __syncthreads();   // O reads done -> next head may overwrite scratch
  }
}

extern "C" void kernel_launch(void* const* d_in, const int* in_sizes, int n_in,
                              void* d_out, int out_size, void* d_ws, size_t ws_size,
                              hipStream_t stream) {
  const float* X  = (const float*)d_in[0];
  const float* am = (const float*)d_in[1];
  const float* Wq = (const float*)d_in[2];
  const float* bq = (const float*)d_in[3];
  const float* Wk = (const float*)d_in[4];
  const float* bk = (const float*)d_in[5];
  const float* Wv = (const float*)d_in[6];
  const float* bv = (const float*)d_in[7];
  const float* bt = (const float*)d_in[8];
  const int*   ri = (const int*)d_in[9];

  u16*   wb   = (u16*)d_ws;
  float* rpbT = (float*)((char*)d_ws + 393216);

  prep_kernel<<<896, 256, 0, stream>>>(Wq, Wk, Wv, bt, ri, wb, rpbT);
  swin_attn_kernel<<<2048, 256, 0, stream>>>(X, wb, bq, bk, bv, rpbT, am, (float*)d_out);
}

// Round 6
// 422.824 us; speedup vs baseline: 1.3307x; 1.3307x over previous
//
#include <hip/hip_runtime.h>

typedef __attribute__((ext_vector_type(8))) short bf16x8;
typedef __attribute__((ext_vector_type(4))) float f32x4;
typedef unsigned short u16;
typedef unsigned int   u32;

__device__ __forceinline__ u16 f2bf(float f) {
  u32 u = __builtin_bit_cast(u32, f);
  u = (u + 0x7FFFu + ((u >> 16) & 1u)) >> 16;
  return (u16)u;
}
__device__ __forceinline__ u16 f2h(float f) {
  _Float16 h = (_Float16)f;
  return __builtin_bit_cast(u16, h);
}
__device__ __forceinline__ float h2f(u16 b) {
  return (float)__builtin_bit_cast(_Float16, b);
}

// ws layout (bytes):
//      0 : Wq|Wk|Wv bf16 [3][256][256]                    (393216 B)
// 393216 : comb f16 [8][64][64][64]                       (4194304 B)
//          comb[h][win][q][k] = bias_table[rel_index[q][k]][h] + mask[win][q][k]
// total 4587520 B

__global__ void prep_kernel(const float* __restrict__ Wq, const float* __restrict__ Wk,
                            const float* __restrict__ Wv, const float* __restrict__ btab,
                            const int* __restrict__ ridx, const float* __restrict__ amask,
                            u16* __restrict__ wb, u16* __restrict__ comb) {
  int bid = blockIdx.x, tid = threadIdx.x;
  if (bid < 768) {
    int gid = bid * 256 + tid;                  // 3 x 65536 weights
    int m = gid >> 16, e = gid & 65535;
    const float* W = (m == 0) ? Wq : (m == 1) ? Wk : Wv;
    wb[gid] = f2bf(W[e]);
  } else {
    int e = (bid - 768) * 256 + tid;            // 2,097,152 elems [h][win][q][k]
    int k = e & 63, q = (e >> 6) & 63, wn = (e >> 12) & 63, h = (e >> 18) & 7;
    float v = btab[ridx[q * 64 + k] * 8 + h] + amask[wn * 4096 + q * 64 + k];
    comb[e] = f2h(v);
  }
}

// One block per window; 4 waves; wave w owns heads 2w, 2w+1 (one at a time).
// LDS 80 KiB:
//   [0,32K)        Xs [64][256] bf16, XOR-swizzled rows of 512B (written once, read-only after)
//   32K + w*12K:   per-wave scratch, 12 KiB:
//     +0    Kh [64][32] bf16, 64B rows, 16B-block rotation by (row>>1)&3
//     +4096 Qh  same layout, pre-scaled by 1/sqrt(32)
//     +8192 VT [32][64] bf16, 128B rows, XOR ^((d&7)<<4)
//     P  [64][64] bf16 overlays Kh+Qh (barrier-separated)
// Output is stored directly from accumulator registers (no LDS bounce).
__global__ __launch_bounds__(256, 2) void swin_attn_kernel(
    const float* __restrict__ X, const u16* __restrict__ Wb,
    const float* __restrict__ bq, const float* __restrict__ bk,
    const float* __restrict__ bv, const u16* __restrict__ comb,
    float* __restrict__ out) {
  __shared__ char smem[81920];

  const int tid = threadIdx.x;
  const int l  = tid & 63;
  const int w  = tid >> 6;
  const int lr = l & 15;
  const int lg = l >> 4;
  const int b  = blockIdx.x;
  const int win = b & 63;

  const float* Xb = X + (size_t)b * (64 * 256);
  float* ob = out + (size_t)b * (64 * 256);

  // ---- stage X -> bf16 LDS ----
#pragma unroll
  for (int it = 0; it < 8; ++it) {
    int c = tid + it * 256;
    int r = c >> 5;
    int k0 = (c & 31) << 3;
    const float* xp = Xb + r * 256 + k0;
    float4 f0 = *(const float4*)xp;
    float4 f1 = *(const float4*)(xp + 4);
    int p0 = (int)((u32)f2bf(f0.x) | ((u32)f2bf(f0.y) << 16));
    int p1 = (int)((u32)f2bf(f0.z) | ((u32)f2bf(f0.w) << 16));
    int p2 = (int)((u32)f2bf(f1.x) | ((u32)f2bf(f1.y) << 16));
    int p3 = (int)((u32)f2bf(f1.z) | ((u32)f2bf(f1.w) << 16));
    int off = (r * 512 + k0 * 2) ^ ((r & 7) << 4);
    *(int4*)(smem + off) = make_int4(p0, p1, p2, p3);
  }
  __syncthreads();

  char* const Kb = smem + 32768 + w * 12288;
  char* const Qb = Kb + 4096;
  char* const Vb = Kb + 8192;
  char* const Pb = Kb;        // overlays K+Q (barrier-separated)

  const float SCALE = 0.17677669529663687f;  // 1/sqrt(32)
  const f32x4 zero = (f32x4)(0.f);

  for (int hl = 0; hl < 2; ++hl) {
    const int h = w * 2 + hl;
    const int cb = w * 64 + hl * 32;     // global channel base of this head

    // ================= fused Q/K/V projection (64x32 each) =================
    {
      float bsq[2], bsk[2], bsv[2];
#pragma unroll
      for (int jf = 0; jf < 2; ++jf) {
        bsq[jf] = bq[cb + jf * 16 + lr];
        bsk[jf] = bk[cb + jf * 16 + lr];
        bsv[jf] = bv[cb + jf * 16 + lr];
      }
      f32x4 aq[4][2], ak[4][2], av[4][2];
#pragma unroll
      for (int rf = 0; rf < 4; ++rf)
#pragma unroll
        for (int jf = 0; jf < 2; ++jf) { aq[rf][jf] = zero; ak[rf][jf] = zero; av[rf][jf] = zero; }

#pragma unroll
      for (int ks = 0; ks < 8; ++ks) {
        int kb = ks * 32 + lg * 8;
        bf16x8 a[4];
#pragma unroll
        for (int rf = 0; rf < 4; ++rf) {
          int row = lr + rf * 16;
          a[rf] = *(const bf16x8*)(smem + ((row * 512 + kb * 2) ^ ((row & 7) << 4)));
        }
#pragma unroll
        for (int jf = 0; jf < 2; ++jf) {
          int wr = (cb + jf * 16 + lr) * 256 + kb;
          bf16x8 wq = *(const bf16x8*)(Wb + wr);
          bf16x8 wk = *(const bf16x8*)(Wb + 65536 + wr);
          bf16x8 wv = *(const bf16x8*)(Wb + 131072 + wr);
#pragma unroll
          for (int rf = 0; rf < 4; ++rf) {
            aq[rf][jf] = __builtin_amdgcn_mfma_f32_16x16x32_bf16(a[rf], wq, aq[rf][jf], 0, 0, 0);
            ak[rf][jf] = __builtin_amdgcn_mfma_f32_16x16x32_bf16(a[rf], wk, ak[rf][jf], 0, 0, 0);
            av[rf][jf] = __builtin_amdgcn_mfma_f32_16x16x32_bf16(a[rf], wv, av[rf][jf], 0, 0, 0);
          }
        }
      }
      // epilogue: K,Q -> rotated 64B rows; V -> VT
#pragma unroll
      for (int rf = 0; rf < 4; ++rf)
#pragma unroll
        for (int jf = 0; jf < 2; ++jf) {
          int dloc = jf * 16 + lr;
#pragma unroll
          for (int reg = 0; reg < 4; ++reg) {
            int i = lg * 4 + reg + rf * 16;
            int off = i * 64 + ((dloc * 2 + (((i >> 1) & 3) << 4)) & 63);
            *(u16*)(Qb + off) = f2bf((aq[rf][jf][reg] + bsq[jf]) * SCALE);
            *(u16*)(Kb + off) = f2bf(ak[rf][jf][reg] + bsk[jf]);
          }
          int i0 = lg * 4 + rf * 16;
          u32 lo = (u32)f2bf(av[rf][jf][0] + bsv[jf]) | ((u32)f2bf(av[rf][jf][1] + bsv[jf]) << 16);
          u32 hi = (u32)f2bf(av[rf][jf][2] + bsv[jf]) | ((u32)f2bf(av[rf][jf][3] + bsv[jf]) << 16);
          int voff = (dloc * 128 + i0 * 2) ^ ((dloc & 7) << 4);
          *(uint2*)(Vb + voff) = make_uint2(lo, hi);
        }
    }
    __syncthreads();   // (1) K/Q/V written -> S-phase reads

    // ================= S^T = K @ Q^T (rows k-token, cols q) + combined bias =================
    float p[4][4][4];  // [rf(k-blocks)][cf(q-blocks)][reg]
    {
      bf16x8 fK[4], fQ[4];
#pragma unroll
      for (int rf = 0; rf < 4; ++rf) {
        int row = lr + rf * 16;
        int off = row * 64 + (((lg + ((row >> 1) & 3)) & 3) << 4);
        fK[rf] = *(const bf16x8*)(Kb + off);
        fQ[rf] = *(const bf16x8*)(Qb + off);
      }
      const u16* cp = comb + (((h << 6) + win) << 12);   // [q][k] f16
#pragma unroll
      for (int rf = 0; rf < 4; ++rf)
#pragma unroll
        for (int cf = 0; cf < 4; ++cf) {
          f32x4 st = __builtin_amdgcn_mfma_f32_16x16x32_bf16(fK[rf], fQ[cf], zero, 0, 0, 0);
          int q = lr + cf * 16;
          int klo = lg * 4 + rf * 16;
          ushort4 cv = *(const ushort4*)(cp + q * 64 + klo);
          p[rf][cf][0] = st[0] + h2f(cv.x);
          p[rf][cf][1] = st[1] + h2f(cv.y);
          p[rf][cf][2] = st[2] + h2f(cv.z);
          p[rf][cf][3] = st[3] + h2f(cv.w);
        }
    }

    // ================= softmax over k per column q =================
#pragma unroll
    for (int cf = 0; cf < 4; ++cf) {
      float mx = p[0][cf][0];
#pragma unroll
      for (int rf = 0; rf < 4; ++rf)
#pragma unroll
        for (int reg = 0; reg < 4; ++reg) mx = fmaxf(mx, p[rf][cf][reg]);
      mx = fmaxf(mx, __shfl_xor(mx, 16));
      mx = fmaxf(mx, __shfl_xor(mx, 32));
      float sum = 0.f;
#pragma unroll
      for (int rf = 0; rf < 4; ++rf)
#pragma unroll
        for (int reg = 0; reg < 4; ++reg) {
          float e = exp2f((p[rf][cf][reg] - mx) * 1.4426950408889634f);
          p[rf][cf][reg] = e;
          sum += e;
        }
      sum += __shfl_xor(sum, 16);
      sum += __shfl_xor(sum, 32);
      float rs = 1.0f / sum;
#pragma unroll
      for (int rf = 0; rf < 4; ++rf)
#pragma unroll
        for (int reg = 0; reg < 4; ++reg) p[rf][cf][reg] *= rs;
    }
    __syncthreads();   // (2) S-phase LDS reads done -> P may overlay K/Q

    // ================= P -> LDS [q][k] bf16 =================
#pragma unroll
    for (int rf = 0; rf < 4; ++rf)
#pragma unroll
      for (int cf = 0; cf < 4; ++cf) {
        int q = lr + cf * 16;
        int k0 = lg * 4 + rf * 16;
        u32 lo = (u32)f2bf(p[rf][cf][0]) | ((u32)f2bf(p[rf][cf][1]) << 16);
        u32 hi = (u32)f2bf(p[rf][cf][2]) | ((u32)f2bf(p[rf][cf][3]) << 16);
        int off = (q * 128 + k0 * 2) ^ ((q & 7) << 4);
        *(uint2*)(Pb + off) = make_uint2(lo, hi);
      }
    __syncthreads();   // (3) P written -> PV reads

    // ================= PV: ctx[64 q][32 d] =================
    f32x4 o[4][2];
#pragma unroll
    for (int rf = 0; rf < 4; ++rf) { o[rf][0] = zero; o[rf][1] = zero; }
#pragma unroll
    for (int ks2 = 0; ks2 < 2; ++ks2) {
      int kb2 = (ks2 * 32 + lg * 8) * 2;
      bf16x8 aP[4];
#pragma unroll
      for (int rf = 0; rf < 4; ++rf) {
        int row = lr + rf * 16;
        aP[rf] = *(const bf16x8*)(Pb + ((row * 128 + kb2) ^ ((row & 7) << 4)));
      }
#pragma unroll
      for (int jf = 0; jf < 2; ++jf) {
        int vr = jf * 16 + lr;
        bf16x8 bV = *(const bf16x8*)(Vb + ((vr * 128 + kb2) ^ ((vr & 7) << 4)));
#pragma unroll
        for (int rf = 0; rf < 4; ++rf)
          o[rf][jf] = __builtin_amdgcn_mfma_f32_16x16x32_bf16(aP[rf], bV, o[rf][jf], 0, 0, 0);
      }
    }
    __syncthreads();   // (4) PV LDS reads done -> next head may overwrite scratch

    // ================= direct register -> global stores (proven 1x write volume) =================
#pragma unroll
    for (int rf = 0; rf < 4; ++rf)
#pragma unroll
      for (int jf = 0; jf < 2; ++jf) {
        int cc = cb + jf * 16 + lr;
#pragma unroll
        for (int reg = 0; reg < 4; ++reg) {
          int i = lg * 4 + reg + rf * 16;
          ob[i * 256 + cc] = o[rf][jf][reg];
        }
      }
  }
}

extern "C" void kernel_launch(void* const* d_in, const int* in_sizes, int n_in,
                              void* d_out, int out_size, void* d_ws, size_t ws_size,
                              hipStream_t stream) {
  const float* X  = (const float*)d_in[0];
  const float* am = (const float*)d_in[1];
  const float* Wq = (const float*)d_in[2];
  const float* bq = (const float*)d_in[3];
  const float* Wk = (const float*)d_in[4];
  const float* bk = (const float*)d_in[5];
  const float* Wv = (const float*)d_in[6];
  const float* bv = (const float*)d_in[7];
  const float* bt = (const float*)d_in[8];
  const int*   ri = (const int*)d_in[9];

  u16* wb   = (u16*)d_ws;
  u16* comb = (u16*)((char*)d_ws + 393216);

  prep_kernel<<<8960, 256, 0, stream>>>(Wq, Wk, Wv, bt, ri, am, wb, comb);
  swin_attn_kernel<<<2048, 256, 0, stream>>>(X, wb, bq, bk, bv, comb, (float*)d_out);
}

// Round 7
// 420.864 us; speedup vs baseline: 1.3369x; 1.0047x over previous
//
#include <hip/hip_runtime.h>

typedef __attribute__((ext_vector_type(8))) short bf16x8;
typedef __attribute__((ext_vector_type(4))) float f32x4;
typedef unsigned short u16;
typedef unsigned int   u32;

__device__ __forceinline__ u16 f2bf(float f) {
  u32 u = __builtin_bit_cast(u32, f);
  u = (u + 0x7FFFu + ((u >> 16) & 1u)) >> 16;
  return (u16)u;
}
__device__ __forceinline__ u16 f2h(float f) {
  _Float16 h = (_Float16)f;
  return __builtin_bit_cast(u16, h);
}
__device__ __forceinline__ float h2f(u16 b) {
  return (float)__builtin_bit_cast(_Float16, b);
}

// ws layout (bytes):
//       0 : Wq|Wk|Wv bf16 [3][256][256]              (393216 B)
//  393216 : comb f16 [8][64][64][64]                 (4194304 B)
//           comb[h][win][q][k] = bias_table[rel_index[q][k]][h] + mask[win][q][k]
// 4587520 : qkv frags bf16 (only if ws_size permits) (201326592 B)
//           per (h,b): 12 slots x 64 lanes x 8 bf16; slot 0-3 = fK[rf],
//           4-7 = fQ[rf], 8-11 = fV[jf*2+ks2]
#define WS_COMB 393216
#define WS_QKV  4587520
#define WS_NEED (4587520ull + 201326592ull)

__global__ void prep_kernel(const float* __restrict__ Wq, const float* __restrict__ Wk,
                            const float* __restrict__ Wv, const float* __restrict__ btab,
                            const int* __restrict__ ridx, const float* __restrict__ amask,
                            u16* __restrict__ wb, u16* __restrict__ comb) {
  int bid = blockIdx.x, tid = threadIdx.x;
  if (bid < 768) {
    int gid = bid * 256 + tid;                  // 3 x 65536 weights
    int m = gid >> 16, e = gid & 65535;
    const float* W = (m == 0) ? Wq : (m == 1) ? Wk : Wv;
    wb[gid] = f2bf(W[e]);
  } else {
    // [wn][q][k] grid; each thread handles all 8 heads (amask read ONCE)
    int e = (bid - 768) * 256 + tid;            // 0..262143
    int qk = e & 4095, wn = e >> 12;
    int q = qk >> 6, k = qk & 63;
    int ri = ridx[q * 64 + k];
    const float4* bt4 = (const float4*)(btab + ri * 8);
    float4 b0 = bt4[0], b1 = bt4[1];
    float m = amask[wn * 4096 + qk];
    float bt[8] = {b0.x, b0.y, b0.z, b0.w, b1.x, b1.y, b1.z, b1.w};
#pragma unroll
    for (int h = 0; h < 8; ++h)
      comb[(h * 64 + wn) * 4096 + qk] = f2h(bt[h] + m);
  }
}

// ===================== split path: kernel A — per-window QKV =====================
// One block per window; 4 waves; wave w -> heads 2w, 2w+1.
// LDS 80 KiB: Xs 32K + per-wave 12K scratch (Kh/Qh rotated, VT swizzled).
// Stores Q/K/V in fragment-linear layout, 16 B/lane fully coalesced.
__global__ __launch_bounds__(256, 2) void qkv_win_kernel(
    const float* __restrict__ X, const u16* __restrict__ Wb,
    const float* __restrict__ bq, const float* __restrict__ bk,
    const float* __restrict__ bv, u16* __restrict__ qkv) {
  __shared__ char smem[81920];

  const int tid = threadIdx.x;
  const int l  = tid & 63;
  const int w  = tid >> 6;
  const int lr = l & 15;
  const int lg = l >> 4;
  const int b  = blockIdx.x;

  const float* Xb = X + (size_t)b * (64 * 256);

  // ---- stage X -> bf16 LDS ----
#pragma unroll
  for (int it = 0; it < 8; ++it) {
    int c = tid + it * 256;
    int r = c >> 5;
    int k0 = (c & 31) << 3;
    const float* xp = Xb + r * 256 + k0;
    float4 f0 = *(const float4*)xp;
    float4 f1 = *(const float4*)(xp + 4);
    int p0 = (int)((u32)f2bf(f0.x) | ((u32)f2bf(f0.y) << 16));
    int p1 = (int)((u32)f2bf(f0.z) | ((u32)f2bf(f0.w) << 16));
    int p2 = (int)((u32)f2bf(f1.x) | ((u32)f2bf(f1.y) << 16));
    int p3 = (int)((u32)f2bf(f1.z) | ((u32)f2bf(f1.w) << 16));
    int off = (r * 512 + k0 * 2) ^ ((r & 7) << 4);
    *(int4*)(smem + off) = make_int4(p0, p1, p2, p3);
  }
  __syncthreads();

  char* const Kb = smem + 32768 + w * 12288;
  char* const Qb = Kb + 4096;
  char* const Vb = Kb + 8192;

  const float SCALE = 0.17677669529663687f;  // 1/sqrt(32)
  const f32x4 zero = (f32x4)(0.f);

  for (int hl = 0; hl < 2; ++hl) {
    const int h = w * 2 + hl;
    const int cb = w * 64 + hl * 32;

    // ---- fused Q/K/V projection (64x32 each) ----
    {
      float bsq[2], bsk[2], bsv[2];
#pragma unroll
      for (int jf = 0; jf < 2; ++jf) {
        bsq[jf] = bq[cb + jf * 16 + lr];
        bsk[jf] = bk[cb + jf * 16 + lr];
        bsv[jf] = bv[cb + jf * 16 + lr];
      }
      f32x4 aq[4][2], ak[4][2], av[4][2];
#pragma unroll
      for (int rf = 0; rf < 4; ++rf)
#pragma unroll
        for (int jf = 0; jf < 2; ++jf) { aq[rf][jf] = zero; ak[rf][jf] = zero; av[rf][jf] = zero; }

#pragma unroll
      for (int ks = 0; ks < 8; ++ks) {
        int kb = ks * 32 + lg * 8;
        bf16x8 a[4];
#pragma unroll
        for (int rf = 0; rf < 4; ++rf) {
          int row = lr + rf * 16;
          a[rf] = *(const bf16x8*)(smem + ((row * 512 + kb * 2) ^ ((row & 7) << 4)));
        }
#pragma unroll
        for (int jf = 0; jf < 2; ++jf) {
          int wr = (cb + jf * 16 + lr) * 256 + kb;
          bf16x8 wq = *(const bf16x8*)(Wb + wr);
          bf16x8 wk = *(const bf16x8*)(Wb + 65536 + wr);
          bf16x8 wv = *(const bf16x8*)(Wb + 131072 + wr);
#pragma unroll
          for (int rf = 0; rf < 4; ++rf) {
            aq[rf][jf] = __builtin_amdgcn_mfma_f32_16x16x32_bf16(a[rf], wq, aq[rf][jf], 0, 0, 0);
            ak[rf][jf] = __builtin_amdgcn_mfma_f32_16x16x32_bf16(a[rf], wk, ak[rf][jf], 0, 0, 0);
            av[rf][jf] = __builtin_amdgcn_mfma_f32_16x16x32_bf16(a[rf], wv, av[rf][jf], 0, 0, 0);
          }
        }
      }
      // epilogue: K,Q -> rotated 64B rows; V -> VT (swizzled)
#pragma unroll
      for (int rf = 0; rf < 4; ++rf)
#pragma unroll
        for (int jf = 0; jf < 2; ++jf) {
          int dloc = jf * 16 + lr;
#pragma unroll
          for (int reg = 0; reg < 4; ++reg) {
            int i = lg * 4 + reg + rf * 16;
            int off = i * 64 + ((dloc * 2 + (((i >> 1) & 3) << 4)) & 63);
            *(u16*)(Qb + off) = f2bf((aq[rf][jf][reg] + bsq[jf]) * SCALE);
            *(u16*)(Kb + off) = f2bf(ak[rf][jf][reg] + bsk[jf]);
          }
          int i0 = lg * 4 + rf * 16;
          u32 lo = (u32)f2bf(av[rf][jf][0] + bsv[jf]) | ((u32)f2bf(av[rf][jf][1] + bsv[jf]) << 16);
          u32 hi = (u32)f2bf(av[rf][jf][2] + bsv[jf]) | ((u32)f2bf(av[rf][jf][3] + bsv[jf]) << 16);
          int voff = (dloc * 128 + i0 * 2) ^ ((dloc & 7) << 4);
          *(uint2*)(Vb + voff) = make_uint2(lo, hi);
        }
    }
    __syncthreads();   // scratch written -> frag reads

    // ---- read MFMA fragments back, store fragment-linear to global ----
    bf16x8 fK[4], fQ[4], fV[4];
#pragma unroll
    for (int rf = 0; rf < 4; ++rf) {
      int row = lr + rf * 16;
      int off = row * 64 + (((lg + ((row >> 1) & 3)) & 3) << 4);
      fK[rf] = *(const bf16x8*)(Kb + off);
      fQ[rf] = *(const bf16x8*)(Qb + off);
    }
#pragma unroll
    for (int jf = 0; jf < 2; ++jf)
#pragma unroll
      for (int ks2 = 0; ks2 < 2; ++ks2) {
        int vr = jf * 16 + lr;
        int kb2 = (ks2 * 32 + lg * 8) * 2;
        fV[jf * 2 + ks2] = *(const bf16x8*)(Vb + ((vr * 128 + kb2) ^ ((vr & 7) << 4)));
      }
    size_t base0 = ((size_t)h * 2048 + b) * 6144 + (size_t)l * 8;
#pragma unroll
    for (int rf = 0; rf < 4; ++rf) *(bf16x8*)(qkv + base0 + rf * 512) = fK[rf];
#pragma unroll
    for (int rf = 0; rf < 4; ++rf) *(bf16x8*)(qkv + base0 + (4 + rf) * 512) = fQ[rf];
#pragma unroll
    for (int j = 0; j < 4; ++j)    *(bf16x8*)(qkv + base0 + (8 + j) * 512) = fV[j];
    __syncthreads();   // frag reads done -> next head may overwrite scratch
  }
}

// ===================== split path: kernel B — attention only =====================
// One block per window; 4 waves; wave w -> heads 2w, 2w+1. LDS 32 KiB (P per wave).
__global__ __launch_bounds__(256, 3) void attn_win_kernel(
    const u16* __restrict__ qkv, const u16* __restrict__ comb,
    float* __restrict__ out) {
  __shared__ char smem[32768];

  const int tid = threadIdx.x;
  const int l  = tid & 63;
  const int w  = tid >> 6;
  const int lr = l & 15;
  const int lg = l >> 4;
  const int b  = blockIdx.x;
  const int win = b & 63;

  float* ob = out + (size_t)b * (64 * 256);
  char* const Pb = smem + w * 8192;
  const f32x4 zero = (f32x4)(0.f);

  for (int hl = 0; hl < 2; ++hl) {
    const int h = w * 2 + hl;
    const int cb = w * 64 + hl * 32;

    size_t base0 = ((size_t)h * 2048 + b) * 6144 + (size_t)l * 8;
    bf16x8 fK[4], fQ[4], fV[4];
#pragma unroll
    for (int rf = 0; rf < 4; ++rf) fK[rf] = *(const bf16x8*)(qkv + base0 + rf * 512);
#pragma unroll
    for (int rf = 0; rf < 4; ++rf) fQ[rf] = *(const bf16x8*)(qkv + base0 + (4 + rf) * 512);
#pragma unroll
    for (int j = 0; j < 4; ++j)    fV[j]  = *(const bf16x8*)(qkv + base0 + (8 + j) * 512);

    // ---- S^T = K @ Q^T + combined bias ----
    float p[4][4][4];
    {
      const u16* cp = comb + (((h << 6) + win) << 12);   // [q][k] f16
#pragma unroll
      for (int rf = 0; rf < 4; ++rf)
#pragma unroll
        for (int cf = 0; cf < 4; ++cf) {
          f32x4 st = __builtin_amdgcn_mfma_f32_16x16x32_bf16(fK[rf], fQ[cf], zero, 0, 0, 0);
          int q = lr + cf * 16;
          int klo = lg * 4 + rf * 16;
          ushort4 cv = *(const ushort4*)(cp + q * 64 + klo);
          p[rf][cf][0] = st[0] + h2f(cv.x);
          p[rf][cf][1] = st[1] + h2f(cv.y);
          p[rf][cf][2] = st[2] + h2f(cv.z);
          p[rf][cf][3] = st[3] + h2f(cv.w);
        }
    }

    // ---- softmax over k per column q ----
#pragma unroll
    for (int cf = 0; cf < 4; ++cf) {
      float mx = p[0][cf][0];
#pragma unroll
      for (int rf = 0; rf < 4; ++rf)
#pragma unroll
        for (int reg = 0; reg < 4; ++reg) mx = fmaxf(mx, p[rf][cf][reg]);
      mx = fmaxf(mx, __shfl_xor(mx, 16));
      mx = fmaxf(mx, __shfl_xor(mx, 32));
      float sum = 0.f;
#pragma unroll
      for (int rf = 0; rf < 4; ++rf)
#pragma unroll
        for (int reg = 0; reg < 4; ++reg) {
          float e = exp2f((p[rf][cf][reg] - mx) * 1.4426950408889634f);
          p[rf][cf][reg] = e;
          sum += e;
        }
      sum += __shfl_xor(sum, 16);
      sum += __shfl_xor(sum, 32);
      float rs = 1.0f / sum;
#pragma unroll
      for (int rf = 0; rf < 4; ++rf)
#pragma unroll
        for (int reg = 0; reg < 4; ++reg) p[rf][cf][reg] *= rs;
    }

    // ---- P -> LDS [q][k] bf16 ----
#pragma unroll
    for (int rf = 0; rf < 4; ++rf)
#pragma unroll
      for (int cf = 0; cf < 4; ++cf) {
        int q = lr + cf * 16;
        int k0 = lg * 4 + rf * 16;
        u32 lo = (u32)f2bf(p[rf][cf][0]) | ((u32)f2bf(p[rf][cf][1]) << 16);
        u32 hi = (u32)f2bf(p[rf][cf][2]) | ((u32)f2bf(p[rf][cf][3]) << 16);
        int off = (q * 128 + k0 * 2) ^ ((q & 7) << 4);
        *(uint2*)(Pb + off) = make_uint2(lo, hi);
      }
    __syncthreads();   // P written -> PV reads

    // ---- PV: ctx[64 q][32 d] ----
    f32x4 o[4][2];
#pragma unroll
    for (int rf = 0; rf < 4; ++rf) { o[rf][0] = zero; o[rf][1] = zero; }
#pragma unroll
    for (int ks2 = 0; ks2 < 2; ++ks2) {
      int kb2 = (ks2 * 32 + lg * 8) * 2;
      bf16x8 aP[4];
#pragma unroll
      for (int rf = 0; rf < 4; ++rf) {
        int row = lr + rf * 16;
        aP[rf] = *(const bf16x8*)(Pb + ((row * 128 + kb2) ^ ((row & 7) << 4)));
      }
#pragma unroll
      for (int jf = 0; jf < 2; ++jf) {
        bf16x8 bV = fV[jf * 2 + ks2];
#pragma unroll
        for (int rf = 0; rf < 4; ++rf)
          o[rf][jf] = __builtin_amdgcn_mfma_f32_16x16x32_bf16(aP[rf], bV, o[rf][jf], 0, 0, 0);
      }
    }

    // ---- direct register -> global stores ----
#pragma unroll
    for (int rf = 0; rf < 4; ++rf)
#pragma unroll
      for (int jf = 0; jf < 2; ++jf) {
        int cc = cb + jf * 16 + lr;
#pragma unroll
        for (int reg = 0; reg < 4; ++reg) {
          int i = lg * 4 + reg + rf * 16;
          ob[i * 256 + cc] = o[rf][jf][reg];
        }
      }
    __syncthreads();   // PV reads done -> next head may overwrite P
  }
}

// ===================== fallback: round-6 fused kernel (proven) =====================
__global__ __launch_bounds__(256, 2) void swin_attn_kernel(
    const float* __restrict__ X, const u16* __restrict__ Wb,
    const float* __restrict__ bq, const float* __restrict__ bk,
    const float* __restrict__ bv, const u16* __restrict__ comb,
    float* __restrict__ out) {
  __shared__ char smem[81920];

  const int tid = threadIdx.x;
  const int l  = tid & 63;
  const int w  = tid >> 6;
  const int lr = l & 15;
  const int lg = l >> 4;
  const int b  = blockIdx.x;
  const int win = b & 63;

  const float* Xb = X + (size_t)b * (64 * 256);
  float* ob = out + (size_t)b * (64 * 256);

#pragma unroll
  for (int it = 0; it < 8; ++it) {
    int c = tid + it * 256;
    int r = c >> 5;
    int k0 = (c & 31) << 3;
    const float* xp = Xb + r * 256 + k0;
    float4 f0 = *(const float4*)xp;
    float4 f1 = *(const float4*)(xp + 4);
    int p0 = (int)((u32)f2bf(f0.x) | ((u32)f2bf(f0.y) << 16));
    int p1 = (int)((u32)f2bf(f0.z) | ((u32)f2bf(f0.w) << 16));
    int p2 = (int)((u32)f2bf(f1.x) | ((u32)f2bf(f1.y) << 16));
    int p3 = (int)((u32)f2bf(f1.z) | ((u32)f2bf(f1.w) << 16));
    int off = (r * 512 + k0 * 2) ^ ((r & 7) << 4);
    *(int4*)(smem + off) = make_int4(p0, p1, p2, p3);
  }
  __syncthreads();

  char* const Kb = smem + 32768 + w * 12288;
  char* const Qb = Kb + 4096;
  char* const Vb = Kb + 8192;
  char* const Pb = Kb;

  const float SCALE = 0.17677669529663687f;
  const f32x4 zero = (f32x4)(0.f);

  for (int hl = 0; hl < 2; ++hl) {
    const int h = w * 2 + hl;
    const int cb = w * 64 + hl * 32;

    {
      float bsq[2], bsk[2], bsv[2];
#pragma unroll
      for (int jf = 0; jf < 2; ++jf) {
        bsq[jf] = bq[cb + jf * 16 + lr];
        bsk[jf] = bk[cb + jf * 16 + lr];
        bsv[jf] = bv[cb + jf * 16 + lr];
      }
      f32x4 aq[4][2], ak[4][2], av[4][2];
#pragma unroll
      for (int rf = 0; rf < 4; ++rf)
#pragma unroll
        for (int jf = 0; jf < 2; ++jf) { aq[rf][jf] = zero; ak[rf][jf] = zero; av[rf][jf] = zero; }

#pragma unroll
      for (int ks = 0; ks < 8; ++ks) {
        int kb = ks * 32 + lg * 8;
        bf16x8 a[4];
#pragma unroll
        for (int rf = 0; rf < 4; ++rf) {
          int row = lr + rf * 16;
          a[rf] = *(const bf16x8*)(smem + ((row * 512 + kb * 2) ^ ((row & 7) << 4)));
        }
#pragma unroll
        for (int jf = 0; jf < 2; ++jf) {
          int wr = (cb + jf * 16 + lr) * 256 + kb;
          bf16x8 wq = *(const bf16x8*)(Wb + wr);
          bf16x8 wk = *(const bf16x8*)(Wb + 65536 + wr);
          bf16x8 wv = *(const bf16x8*)(Wb + 131072 + wr);
#pragma unroll
          for (int rf = 0; rf < 4; ++rf) {
            aq[rf][jf] = __builtin_amdgcn_mfma_f32_16x16x32_bf16(a[rf], wq, aq[rf][jf], 0, 0, 0);
            ak[rf][jf] = __builtin_amdgcn_mfma_f32_16x16x32_bf16(a[rf], wk, ak[rf][jf], 0, 0, 0);
            av[rf][jf] = __builtin_amdgcn_mfma_f32_16x16x32_bf16(a[rf], wv, av[rf][jf], 0, 0, 0);
          }
        }
      }
#pragma unroll
      for (int rf = 0; rf < 4; ++rf)
#pragma unroll
        for (int jf = 0; jf < 2; ++jf) {
          int dloc = jf * 16 + lr;
#pragma unroll
          for (int reg = 0; reg < 4; ++reg) {
            int i = lg * 4 + reg + rf * 16;
            int off = i * 64 + ((dloc * 2 + (((i >> 1) & 3) << 4)) & 63);
            *(u16*)(Qb + off) = f2bf((aq[rf][jf][reg] + bsq[jf]) * SCALE);
            *(u16*)(Kb + off) = f2bf(ak[rf][jf][reg] + bsk[jf]);
          }
          int i0 = lg * 4 + rf * 16;
          u32 lo = (u32)f2bf(av[rf][jf][0] + bsv[jf]) | ((u32)f2bf(av[rf][jf][1] + bsv[jf]) << 16);
          u32 hi = (u32)f2bf(av[rf][jf][2] + bsv[jf]) | ((u32)f2bf(av[rf][jf][3] + bsv[jf]) << 16);
          int voff = (dloc * 128 + i0 * 2) ^ ((dloc & 7) << 4);
          *(uint2*)(Vb + voff) = make_uint2(lo, hi);
        }
    }
    __syncthreads();

    float p[4][4][4];
    {
      bf16x8 fK[4], fQ[4];
#pragma unroll
      for (int rf = 0; rf < 4; ++rf) {
        int row = lr + rf * 16;
        int off = row * 64 + (((lg + ((row >> 1) & 3)) & 3) << 4);
        fK[rf] = *(const bf16x8*)(Kb + off);
        fQ[rf] = *(const bf16x8*)(Qb + off);
      }
      const u16* cp = comb + (((h << 6) + win) << 12);
#pragma unroll
      for (int rf = 0; rf < 4; ++rf)
#pragma unroll
        for (int cf = 0; cf < 4; ++cf) {
          f32x4 st = __builtin_amdgcn_mfma_f32_16x16x32_bf16(fK[rf], fQ[cf], zero, 0, 0, 0);
          int q = lr + cf * 16;
          int klo = lg * 4 + rf * 16;
          ushort4 cv = *(const ushort4*)(cp + q * 64 + klo);
          p[rf][cf][0] = st[0] + h2f(cv.x);
          p[rf][cf][1] = st[1] + h2f(cv.y);
          p[rf][cf][2] = st[2] + h2f(cv.z);
          p[rf][cf][3] = st[3] + h2f(cv.w);
        }
    }

#pragma unroll
    for (int cf = 0; cf < 4; ++cf) {
      float mx = p[0][cf][0];
#pragma unroll
      for (int rf = 0; rf < 4; ++rf)
#pragma unroll
        for (int reg = 0; reg < 4; ++reg) mx = fmaxf(mx, p[rf][cf][reg]);
      mx = fmaxf(mx, __shfl_xor(mx, 16));
      mx = fmaxf(mx, __shfl_xor(mx, 32));
      float sum = 0.f;
#pragma unroll
      for (int rf = 0; rf < 4; ++rf)
#pragma unroll
        for (int reg = 0; reg < 4; ++reg) {
          float e = exp2f((p[rf][cf][reg] - mx) * 1.4426950408889634f);
          p[rf][cf][reg] = e;
          sum += e;
        }
      sum += __shfl_xor(sum, 16);
      sum += __shfl_xor(sum, 32);
      float rs = 1.0f / sum;
#pragma unroll
      for (int rf = 0; rf < 4; ++rf)
#pragma unroll
        for (int reg = 0; reg < 4; ++reg) p[rf][cf][reg] *= rs;
    }
    __syncthreads();

#pragma unroll
    for (int rf = 0; rf < 4; ++rf)
#pragma unroll
      for (int cf = 0; cf < 4; ++cf) {
        int q = lr + cf * 16;
        int k0 = lg * 4 + rf * 16;
        u32 lo = (u32)f2bf(p[rf][cf][0]) | ((u32)f2bf(p[rf][cf][1]) << 16);
        u32 hi = (u32)f2bf(p[rf][cf][2]) | ((u32)f2bf(p[rf][cf][3]) << 16);
        int off = (q * 128 + k0 * 2) ^ ((q & 7) << 4);
        *(uint2*)(Pb + off) = make_uint2(lo, hi);
      }
    __syncthreads();

    f32x4 o[4][2];
#pragma unroll
    for (int rf = 0; rf < 4; ++rf) { o[rf][0] = zero; o[rf][1] = zero; }
#pragma unroll
    for (int ks2 = 0; ks2 < 2; ++ks2) {
      int kb2 = (ks2 * 32 + lg * 8) * 2;
      bf16x8 aP[4];
#pragma unroll
      for (int rf = 0; rf < 4; ++rf) {
        int row = lr + rf * 16;
        aP[rf] = *(const bf16x8*)(Pb + ((row * 128 + kb2) ^ ((row & 7) << 4)));
      }
#pragma unroll
      for (int jf = 0; jf < 2; ++jf) {
        int vr = jf * 16 + lr;
        bf16x8 bV = *(const bf16x8*)(Vb + ((vr * 128 + kb2) ^ ((vr & 7) << 4)));
#pragma unroll
        for (int rf = 0; rf < 4; ++rf)
          o[rf][jf] = __builtin_amdgcn_mfma_f32_16x16x32_bf16(aP[rf], bV, o[rf][jf], 0, 0, 0);
      }
    }
    __syncthreads();

#pragma unroll
    for (int rf = 0; rf < 4; ++rf)
#pragma unroll
      for (int jf = 0; jf < 2; ++jf) {
        int cc = cb + jf * 16 + lr;
#pragma unroll
        for (int reg = 0; reg < 4; ++reg) {
          int i = lg * 4 + reg + rf * 16;
          ob[i * 256 + cc] = o[rf][jf][reg];
        }
      }
  }
}

extern "C" void kernel_launch(void* const* d_in, const int* in_sizes, int n_in,
                              void* d_out, int out_size, void* d_ws, size_t ws_size,
                              hipStream_t stream) {
  const float* X  = (const float*)d_in[0];
  const float* am = (const float*)d_in[1];
  const float* Wq = (const float*)d_in[2];
  const float* bq = (const float*)d_in[3];
  const float* Wk = (const float*)d_in[4];
  const float* bk = (const float*)d_in[5];
  const float* Wv = (const float*)d_in[6];
  const float* bv = (const float*)d_in[7];
  const float* bt = (const float*)d_in[8];
  const int*   ri = (const int*)d_in[9];

  u16* wb   = (u16*)d_ws;
  u16* comb = (u16*)((char*)d_ws + WS_COMB);
  u16* qkv  = (u16*)((char*)d_ws + WS_QKV);

  prep_kernel<<<1792, 256, 0, stream>>>(Wq, Wk, Wv, bt, ri, am, wb, comb);
  if (ws_size >= WS_NEED) {
    qkv_win_kernel<<<2048, 256, 0, stream>>>(X, wb, bq, bk, bv, qkv);
    attn_win_kernel<<<2048, 256, 0, stream>>>(qkv, comb, (float*)d_out);
  } else {
    swin_attn_kernel<<<2048, 256, 0, stream>>>(X, wb, bq, bk, bv, comb, (float*)d_out);
  }
}